// Round 11
// baseline (315.590 us; speedup 1.0000x reference)
//
#include <hip/hip_runtime.h>
#include <math.h>

#define BN_SCALE 0.99999500003749967f
#define RRELU_SLOPE 0.22916666666666666f

static __device__ __forceinline__ float leaky(float v) { return v > 0.f ? v : 0.01f * v; }

typedef __attribute__((ext_vector_type(8))) short bf16x8;
typedef __attribute__((ext_vector_type(4))) float f32x4;

static __device__ __forceinline__ unsigned short f2bf(float f) {
  unsigned u = __builtin_bit_cast(unsigned, f);
  u = (u + 0x7FFFu + ((u >> 16) & 1u)) >> 16;
  return (unsigned short)u;
}

// ---------------------------------------------------------------------------
// big: blocks 0..1012 = fe (4 waves, 1 seq/wave, inline A-frag build);
// blocks 1013..3284 = w1 transpose -> w1T bf16; blocks 3285.. = Wgagb frags,
// folded biases, subjectsA zero, act1pre = cb1 seed.
// ---------------------------------------------------------------------------
__global__ __launch_bounds__(256) void big_kernel(
    const float* __restrict__ x,
    const float* __restrict__ w1c, const float* __restrict__ b1c,
    const float* __restrict__ g1,  const float* __restrict__ bb1,
    const float* __restrict__ w2c, const float* __restrict__ b2c,
    const float* __restrict__ g2,  const float* __restrict__ bb2,
    const float* __restrict__ w3c, const float* __restrict__ b3c,
    const float* __restrict__ g3,  const float* __restrict__ bb3,
    const float* __restrict__ fcw, const float* __restrict__ fcb,
    const float* __restrict__ w1,  const float* __restrict__ b1,
    const float* __restrict__ cw1, const float* __restrict__ cb1,
    unsigned short* __restrict__ act3,
    unsigned short* __restrict__ bfragGG,
    float* __restrict__ bgagb,
    unsigned short* __restrict__ subjectsA,
    unsigned short* __restrict__ w1T,
    float* __restrict__ act1pre)
{
  __shared__ __align__(16) char smem[27648];
  const int t = threadIdx.x;

  if (blockIdx.x < 1013) {
    // ================= fe phase: wave-autonomous =================
    const int wv = t >> 6, lane = t & 63, quad = lane >> 4, lr = lane & 15;
    const int n = blockIdx.x * 4 + wv;
    if (n >= 4050) return;

    char* A = smem + wv * 6912;
    unsigned short* buf = (unsigned short*)A;   // s1t 194rx16sh / s2t 98rx32sh overlaid
    float* be2 = (float*)(A + 6272);            // 64
    float* be3 = (float*)(A + 6528);            // 96

    // inline conv2 A-frags (bn-folded, bf16)
    bf16x8 a2[4][2];
#pragma unroll
    for (int mt = 0; mt < 4; ++mt) {
      const int c = mt * 16 + lr;
      const float gs = g2[c] * BN_SCALE;
#pragma unroll
      for (int kc = 0; kc < 2; ++kc) {
        bf16x8 fr;
#pragma unroll
        for (int j = 0; j < 8; ++j) {
          const int k = quad * 8 + j;
          float v;
          if (kc == 0) { const int tap = k >> 4, ci = k & 15; v = w2c[c * 48 + ci * 3 + tap] * gs; }
          else         { v = (k < 16) ? w2c[c * 48 + k * 3 + 2] * gs : 0.f; }
          fr[j] = (short)f2bf(v);
        }
        a2[mt][kc] = fr;
      }
    }

    be2[lane] = b2c[lane] * (g2[lane] * BN_SCALE) + bb2[lane];
    be3[lane] = b3c[lane] * (g3[lane] * BN_SCALE) + bb3[lane];
    if (lane < 32) be3[64 + lane] = b3c[64 + lane] * (g3[64 + lane] * BN_SCALE) + bb3[64 + lane];
    ((unsigned*)buf)[1488 + lane] = 0;          // s1t pad rows 186..193

    const int cp = lane & 7;
    float u[4][3], bbr[4];
#pragma unroll
    for (int d = 0; d < 4; ++d) {
      const int c = cp * 4 + d;
      const float gs = g1[c] * BN_SCALE;
      u[d][0] = w1c[c * 3 + 0] * gs;
      u[d][1] = w1c[c * 3 + 1] * gs;
      u[d][2] = w1c[c * 3 + 2] * gs;
      bbr[d] = b1c[c] * gs + bb1[c];
    }

    // stage 1: conv1+bn+leaky+pool -> buf rows 0..185
    const float* xr = x + (size_t)n * 375;
    for (int o = lane; o < 1488; o += 64) {
      const int l = o >> 3;
      const int p = 2 * l;
      const float x0 = xr[p], x1 = xr[p + 1], x2 = xr[p + 2], x3 = xr[p + 3];
      unsigned pk = 0;
#pragma unroll
      for (int uu = 0; uu < 2; ++uu) {
        float m = -3.4e38f;
#pragma unroll
        for (int dc = 0; dc < 2; ++dc) {
          const int d = uu * 2 + dc;
          const float v0 = fmaf(x0, u[d][0], fmaf(x1, u[d][1], fmaf(x2, u[d][2], bbr[d])));
          const float v1 = fmaf(x1, u[d][0], fmaf(x2, u[d][1], fmaf(x3, u[d][2], bbr[d])));
          m = fmaxf(m, fmaxf(leaky(v0), leaky(v1)));
        }
        pk |= (unsigned)f2bf(m) << (16 * uu);
      }
      ((unsigned*)buf)[l * 8 + cp] = pk;
    }

    float be2r[4][4];
#pragma unroll
    for (int mt = 0; mt < 4; ++mt)
#pragma unroll
      for (int r = 0; r < 4; ++r) be2r[mt][r] = be2[mt * 16 + quad * 4 + r];

    // conv2: 12 n-tiles (s2t overlays s1t, ordering safe within wave)
#pragma unroll 2
    for (int nt = 0; nt < 12; ++nt) {
      const int nrow = nt * 16 + lr;
      bf16x8 b0 = *(const bf16x8*)(buf + (nrow + (quad >> 1)) * 16 + (quad & 1) * 8);
      bf16x8 b1 = *(const bf16x8*)(buf + (nrow + 2) * 16 + (quad & 1) * 8);
      f32x4 acc[4];
#pragma unroll
      for (int mt = 0; mt < 4; ++mt)
#pragma unroll
        for (int r = 0; r < 4; ++r) acc[mt][r] = be2r[mt][r];
#pragma unroll
      for (int mt = 0; mt < 4; ++mt)
        acc[mt] = __builtin_amdgcn_mfma_f32_16x16x32_bf16(a2[mt][0], b0, acc[mt], 0, 0, 0);
#pragma unroll
      for (int mt = 0; mt < 4; ++mt)
        acc[mt] = __builtin_amdgcn_mfma_f32_16x16x32_bf16(a2[mt][1], b1, acc[mt], 0, 0, 0);
#pragma unroll
      for (int mt = 0; mt < 4; ++mt) {
        float o[4];
#pragma unroll
        for (int r = 0; r < 4; ++r) {
          const float v = leaky(acc[mt][r]);
          o[r] = fmaxf(v, __shfl_xor(v, 1));
        }
        if ((lr & 1) == 0) {
          const int np = nrow >> 1;
          if (np <= 91) {
            const float m0 = fmaxf(o[0], o[1]);
            const float m1 = fmaxf(o[2], o[3]);
            const unsigned pk = (unsigned)f2bf(m0) | ((unsigned)f2bf(m1) << 16);
            ((unsigned*)buf)[np * 16 + mt * 4 + quad] = pk;
          }
        }
      }
    }

    // zero s2t pad rows 92..97
    ((unsigned*)buf)[1472 + lane] = 0;
    if (lane < 32) ((unsigned*)buf)[1536 + lane] = 0;

    // conv3: 6x6 tiles, inline A-frags; epilogue -> act3
    unsigned short* actr = act3 + (size_t)n * 2176;
    for (int mt = 0; mt < 6; ++mt) {
      const int c = mt * 16 + lr;
      const float gs3v = g3[c] * BN_SCALE;
      bf16x8 a3[3];
#pragma unroll
      for (int tap = 0; tap < 3; ++tap) {
        bf16x8 fr;
#pragma unroll
        for (int j = 0; j < 8; ++j) {
          const int ci = quad * 8 + j;
          fr[j] = (short)f2bf(w3c[c * 96 + ci * 3 + tap] * gs3v);
        }
        a3[tap] = fr;
      }
      float be3r[4];
#pragma unroll
      for (int r = 0; r < 4; ++r) be3r[r] = be3[mt * 16 + quad * 4 + r];
#pragma unroll
      for (int nt = 0; nt < 6; ++nt) {
        const int nrow = nt * 16 + lr;
        f32x4 acc;
#pragma unroll
        for (int r = 0; r < 4; ++r) acc[r] = be3r[r];
#pragma unroll
        for (int tap = 0; tap < 3; ++tap) {
          bf16x8 b = *(const bf16x8*)(buf + (nrow + tap) * 32 + quad * 8);
          acc = __builtin_amdgcn_mfma_f32_16x16x32_bf16(a3[tap], b, acc, 0, 0, 0);
        }
        float o[4];
#pragma unroll
        for (int r = 0; r < 4; ++r) {
          const float v = leaky(acc[r]);
          o[r] = fmaxf(v, __shfl_xor(v, 1));
        }
        if ((lr & 1) == 0) {
          const int np = nrow >> 1;
          if (np <= 44) {
            const int mp = mt * 8 + quad * 2;
            actr[mp * 45 + np] = f2bf(fmaxf(o[0], o[1]));
            actr[(mp + 1) * 45 + np] = f2bf(fmaxf(o[2], o[3]));
          }
        }
      }
    }
    if (lane < 16) actr[2160 + lane] = 0;
    return;
  }

  const int sb = blockIdx.x - 1013;
  if (sb < 2272) {
    // ================= w1 transpose -> w1T =================
    float (*tile)[65] = (float(*)[65])smem;
    const int kt = sb >> 4;
    const int ntb = sb & 15;
    const int k0 = kt * 64, n0 = ntb * 64;
#pragma unroll 4
    for (int i = 0; i < 16; ++i) {
      const int idx = i * 256 + t;
      const int kk = idx >> 6, nn = idx & 63;
      const int k = k0 + kk;
      tile[kk][nn] = (k < 9045) ? cw1[(size_t)k * 1024 + n0 + nn] : 0.f;
    }
    __syncthreads();
#pragma unroll 4
    for (int i = 0; i < 8; ++i) {
      const int idx = i * 256 + t;
      const int nn = idx >> 5;
      const int kp = (idx & 31) * 2;
      const unsigned lo = f2bf(tile[kp][nn]);
      const unsigned hi = f2bf(tile[kp + 1][nn]);
      ((unsigned*)w1T)[(size_t)(n0 + nn) * 4544 + (k0 >> 1) + (idx & 31)] = lo | (hi << 16);
    }
    return;
  }

  const int item = (sb - 2272) * 256 + t;
  if (item < 17408) {                    // Wgagb B-frags
    const int chunk = item >> 8;
    const int rem = item & 255;
    const int nt = rem >> 6;
    const int lane = rem & 63;
    const int lr = lane & 15, quad = lane >> 4;
    const int nn = nt * 16 + lr;
    const int off = (nn >= 32) ? 32 : 0;
    const int nj = nn & 31;
    float w1col[32];
#pragma unroll 8
    for (int q = 0; q < 32; ++q) w1col[q] = w1[(q + off) * 32 + nj];
#pragma unroll
    for (int j = 0; j < 8; ++j) {
      const int k = chunk * 32 + quad * 8 + j;
      float v = 0.f;
      if (k < 2160) {
        const float* fr = fcw + (size_t)k * 32;
#pragma unroll 8
        for (int q = 0; q < 32; ++q) v = fmaf(fr[q], w1col[q], v);
      }
      bfragGG[(size_t)item * 8 + j] = f2bf(v);
    }
  } else if (item < 17472) {             // folded biases
    const int nn = item - 17408;
    const int off = (nn >= 32) ? 32 : 0;
    const int nj = nn & 31;
    float s = (nn < 32) ? b1[nj] : 0.f;
    for (int q = 0; q < 32; ++q) s = fmaf(fcb[q], w1[(q + off) * 32 + nj], s);
    bgagb[nn] = s;
  } else if (item < 53696) {             // zero subjectsA (283*1024 sh = 36224 uint4)
    const int idx = item - 17472;
    uint4 z = {0u, 0u, 0u, 0u};
    ((uint4*)subjectsA)[idx] = z;
  } else if (item < 61376) {             // seed act1pre = cb1 (30x1024, float4)
    const int idx = item - 53696;
    const int r = idx >> 8, q = idx & 255;
    const float4 v = *(const float4*)(cb1 + q * 4);
    *(float4*)(act1pre + (size_t)r * 1024 + q * 4) = v;
  }
}

// ---------------------------------------------------------------------------
// gagb: 254 blocks x 16 rows; 4 waves split K (17 chunks each); LDS reduce.
// ---------------------------------------------------------------------------
__global__ __launch_bounds__(256) void gagb_kernel(
    const unsigned short* __restrict__ act3,
    const unsigned short* __restrict__ bfragGG,
    const float* __restrict__ bgagb,
    float* __restrict__ Ga, float* __restrict__ Gb)
{
  __shared__ f32x4 sred[3][4][64];
  const int t = threadIdx.x;
  const int wv = t >> 6, lane = t & 63, quad = lane >> 4, lr = lane & 15;
  const int m0 = blockIdx.x * 16;
  const int arow = min(m0 + lr, 4049);

  f32x4 acc[4] = {};
  const int c0 = wv * 17;
  for (int chunk = c0; chunk < c0 + 17; ++chunk) {
    const bf16x8 a = *(const bf16x8*)(act3 + (size_t)arow * 2176 + chunk * 32 + quad * 8);
#pragma unroll
    for (int nt = 0; nt < 4; ++nt) {
      const bf16x8 b = *(const bf16x8*)(bfragGG + ((size_t)(chunk * 4 + nt) * 64 + lane) * 8);
      acc[nt] = __builtin_amdgcn_mfma_f32_16x16x32_bf16(a, b, acc[nt], 0, 0, 0);
    }
  }
  if (wv > 0) {
#pragma unroll
    for (int nt = 0; nt < 4; ++nt) sred[wv - 1][nt][lane] = acc[nt];
  }
  __syncthreads();
  if (wv == 0) {
#pragma unroll
    for (int nt = 0; nt < 4; ++nt) {
      f32x4 s = acc[nt];
#pragma unroll
      for (int q = 0; q < 3; ++q) {
        const f32x4 o = sred[q][nt][lane];
#pragma unroll
        for (int r = 0; r < 4; ++r) s[r] += o[r];
      }
      const int col = nt * 16 + lr;
      const float bias = bgagb[col];
#pragma unroll
      for (int r = 0; r < 4; ++r) {
        const int row = m0 + quad * 4 + r;
        if (row < 4050) {
          const float v = s[r] + bias;
          if (col < 32) Ga[row * 32 + col] = v;
          else          Gb[row * 32 + (col - 32)] = v;
        }
      }
    }
  }
}

// ---------------------------------------------------------------------------
// sim: 960 blocks = 30 subjects x 32 chunks; writes bf16 MFMA A-fragments.
// ---------------------------------------------------------------------------
__global__ __launch_bounds__(256) void sim_kernel(
    const float* __restrict__ Ga, const float* __restrict__ Gb,
    const float* __restrict__ w2, const float* __restrict__ b2,
    const float* __restrict__ w3, const float* __restrict__ b3,
    const float* __restrict__ w4, const float* __restrict__ b4,
    unsigned short* __restrict__ subjectsA)
{
  __shared__ float sGa[135 * 36];
  __shared__ float sGb[135 * 36];
  __shared__ float sw2[512], sw3[128], sw4[8];
  __shared__ float sb2[16], sb3[8], sb4v[1];

  const int t = threadIdx.x;
  const int b = blockIdx.x >> 5;
  const int c = blockIdx.x & 31;

  for (int i = t; i < 4320; i += 256) {
    const int r = i >> 5, col = i & 31;
    sGa[r * 36 + col] = Ga[b * 4320 + i];
    sGb[r * 36 + col] = Gb[b * 4320 + i];
  }
  for (int i = t; i < 512; i += 256) sw2[i] = w2[i];
  if (t < 128) sw3[t] = w3[t];
  if (t < 8) sw4[t] = w4[t];
  if (t < 16) sb2[t] = b2[t];
  if (t < 8) sb3[t] = b3[t];
  if (t == 0) sb4v[0] = b4[0];
  __syncthreads();

  const int mtile = b >> 4, lrm = b & 15;
  const int pend = min(9045, (c + 1) * 283);
  for (int p = c * 283 + t; p < pend; p += 256) {
    int i = (int)((269.0f - sqrtf((float)(72361 - 8 * p))) * 0.5f);
    i = max(0, min(133, i));
    while (134 * (i + 1) - ((i + 1) * i) / 2 <= p) ++i;
    while (134 * i - (i * (i - 1)) / 2 > p) --i;
    const int j = i + 1 + (p - (134 * i - (i * (i - 1)) / 2));

    float h1[32];
#pragma unroll
    for (int q = 0; q < 8; ++q) {
      const float4 va = *(const float4*)(&sGa[i * 36 + 4 * q]);
      const float4 vb = *(const float4*)(&sGb[j * 36 + 4 * q]);
      h1[4 * q + 0] = fmaxf(va.x + vb.x, 0.f);
      h1[4 * q + 1] = fmaxf(va.y + vb.y, 0.f);
      h1[4 * q + 2] = fmaxf(va.z + vb.z, 0.f);
      h1[4 * q + 3] = fmaxf(va.w + vb.w, 0.f);
    }

    float h2[16];
#pragma unroll
    for (int jj = 0; jj < 16; ++jj) h2[jj] = sb2[jj];
#pragma unroll 8
    for (int ii = 0; ii < 32; ++ii) {
      const float av = h1[ii];
      const float4* wr = reinterpret_cast<const float4*>(&sw2[ii * 16]);
#pragma unroll
      for (int r = 0; r < 4; ++r) {
        float4 w = wr[r];
        h2[4 * r + 0] = fmaf(av, w.x, h2[4 * r + 0]);
        h2[4 * r + 1] = fmaf(av, w.y, h2[4 * r + 1]);
        h2[4 * r + 2] = fmaf(av, w.z, h2[4 * r + 2]);
        h2[4 * r + 3] = fmaf(av, w.w, h2[4 * r + 3]);
      }
    }
#pragma unroll
    for (int jj = 0; jj < 16; ++jj) h2[jj] = fmaxf(h2[jj], 0.f);

    float h3[8];
#pragma unroll
    for (int jj = 0; jj < 8; ++jj) h3[jj] = sb3[jj];
#pragma unroll
    for (int ii = 0; ii < 16; ++ii) {
      const float av = h2[ii];
      const float4* wr = reinterpret_cast<const float4*>(&sw3[ii * 8]);
#pragma unroll
      for (int r = 0; r < 2; ++r) {
        float4 w = wr[r];
        h3[4 * r + 0] = fmaf(av, w.x, h3[4 * r + 0]);
        h3[4 * r + 1] = fmaf(av, w.y, h3[4 * r + 1]);
        h3[4 * r + 2] = fmaf(av, w.z, h3[4 * r + 2]);
        h3[4 * r + 3] = fmaf(av, w.w, h3[4 * r + 3]);
      }
    }
#pragma unroll
    for (int jj = 0; jj < 8; ++jj) h3[jj] = fmaxf(h3[jj], 0.f);

    float z = sb4v[0];
#pragma unroll
    for (int ii = 0; ii < 8; ++ii) z = fmaf(h3[ii], sw4[ii], z);

    const float az = fabsf(z);
    const float e = __expf(-2.f * az);
    const float rr = (1.f - e) / (1.f + e);
    const float val = copysignf(rr, z);

    const int chunk = p >> 5, q8 = (p & 31) >> 3, jj2 = p & 7;
    subjectsA[chunk * 1024 + mtile * 512 + (q8 * 16 + lrm) * 8 + jj2] = f2bf(val);
  }
}

// ---------------------------------------------------------------------------
// c1 (MFMA, atomic): act1pre += subjects @ w1. 256 blocks x 4 waves.
// ---------------------------------------------------------------------------
__global__ __launch_bounds__(256) void c1_kernel(
    const unsigned short* __restrict__ subjectsA,
    const unsigned short* __restrict__ w1T,
    float* __restrict__ act1pre)
{
  const int t = threadIdx.x;
  const int wv = t >> 6, lane = t & 63, quad = lane >> 4, lr = lane & 15;
  const int job = blockIdx.x * 4 + wv;
  const int ng = job & 15;
  const int kg = job >> 4;
  const int c0 = kg * 5;
  const int cend = min(283, c0 + 5);

  f32x4 acc[2][4] = {};
  for (int ch = c0; ch < cend; ++ch) {
    const bf16x8 a0 = *(const bf16x8*)(subjectsA + ch * 1024 + lane * 8);
    const bf16x8 a1 = *(const bf16x8*)(subjectsA + ch * 1024 + 512 + lane * 8);
#pragma unroll
    for (int nt = 0; nt < 4; ++nt) {
      const int col = (ng * 4 + nt) * 16 + lr;
      const bf16x8 b = *(const bf16x8*)(w1T + (size_t)col * 9088 + ch * 32 + quad * 8);
      acc[0][nt] = __builtin_amdgcn_mfma_f32_16x16x32_bf16(a0, b, acc[0][nt], 0, 0, 0);
      acc[1][nt] = __builtin_amdgcn_mfma_f32_16x16x32_bf16(a1, b, acc[1][nt], 0, 0, 0);
    }
  }
#pragma unroll
  for (int mt = 0; mt < 2; ++mt)
#pragma unroll
    for (int r = 0; r < 4; ++r) {
      const int m = mt * 16 + quad * 4 + r;
      if (m < 30) {
#pragma unroll
        for (int nt = 0; nt < 4; ++nt) {
          const int col = (ng * 4 + nt) * 16 + lr;
          atomicAdd(&act1pre[(size_t)m * 1024 + col], acc[mt][nt][r]);
        }
      }
    }
}

// ---------------------------------------------------------------------------
// tail: 30 blocks x 1024 thr. rrelu(act1pre) -> GEMM2 (4-way ksplit) -> relu
// -> GEMM3 (16-way ksplit) -> relu -> GEMM4 -> log_softmax.
// ---------------------------------------------------------------------------
__global__ __launch_bounds__(1024) void tail_kernel(
    const float* __restrict__ act1pre,
    const float* __restrict__ w2, const float* __restrict__ cb2,
    const float* __restrict__ w3, const float* __restrict__ cb3,
    const float* __restrict__ w4, const float* __restrict__ cb4,
    float* __restrict__ out)
{
  __shared__ float sc1[1024];
  __shared__ float sp[1024];
  __shared__ float sact2[256];
  __shared__ float sc3[64];
  __shared__ float slg[3];
  const int r = blockIdx.x, t = threadIdx.x;

  {
    const float s = act1pre[(size_t)r * 1024 + t];
    sc1[t] = s >= 0.f ? s : RRELU_SLOPE * s;
  }
  __syncthreads();
  {
    const int col = t & 255, ks = t >> 8;
    float acc = 0.f;
    const int k0 = ks * 256;
    for (int kk = k0; kk < k0 + 256; kk += 4) {
      const float4 a = *reinterpret_cast<const float4*>(&sc1[kk]);
      acc = fmaf(a.x, w2[(kk + 0) * 256 + col], acc);
      acc = fmaf(a.y, w2[(kk + 1) * 256 + col], acc);
      acc = fmaf(a.z, w2[(kk + 2) * 256 + col], acc);
      acc = fmaf(a.w, w2[(kk + 3) * 256 + col], acc);
    }
    sp[t] = acc;
  }
  __syncthreads();
  if (t < 256) sact2[t] = fmaxf(cb2[t] + sp[t] + sp[t + 256] + sp[t + 512] + sp[t + 768], 0.f);
  __syncthreads();
  {
    const int col = t & 63, ks = t >> 6;   // 16 splits of 16
    float acc = 0.f;
    const int k0 = ks * 16;
#pragma unroll 4
    for (int kk = k0; kk < k0 + 16; ++kk)
      acc = fmaf(sact2[kk], w3[kk * 64 + col], acc);
    sp[t] = acc;
  }
  __syncthreads();
  if (t < 64) {
    float s = cb3[t];
#pragma unroll
    for (int q = 0; q < 16; ++q) s += sp[q * 64 + t];
    sc3[t] = fmaxf(s, 0.f);
  }
  __syncthreads();
  if (t < 3) {
    float acc = cb4[t];
#pragma unroll
    for (int kk = 0; kk < 64; ++kk) acc = fmaf(sc3[kk], w4[kk * 3 + t], acc);
    slg[t] = acc;
  }
  __syncthreads();
  if (t == 0) {
    const float m = fmaxf(slg[0], fmaxf(slg[1], slg[2]));
    const float se = __expf(slg[0] - m) + __expf(slg[1] - m) + __expf(slg[2] - m);
    const float lse = m + logf(se);
    out[r * 3 + 0] = slg[0] - lse;
    out[r * 3 + 1] = slg[1] - lse;
    out[r * 3 + 2] = slg[2] - lse;
  }
}

extern "C" void kernel_launch(void* const* d_in, const int* in_sizes, int n_in,
                              void* d_out, int out_size, void* d_ws, size_t ws_size,
                              hipStream_t stream) {
  const float* x    = (const float*)d_in[0];
  const float* w1c  = (const float*)d_in[1];
  const float* b1c  = (const float*)d_in[2];
  const float* g1   = (const float*)d_in[3];
  const float* bb1  = (const float*)d_in[4];
  const float* w2c  = (const float*)d_in[5];
  const float* b2c  = (const float*)d_in[6];
  const float* g2   = (const float*)d_in[7];
  const float* bb2  = (const float*)d_in[8];
  const float* w3c  = (const float*)d_in[9];
  const float* b3c  = (const float*)d_in[10];
  const float* g3   = (const float*)d_in[11];
  const float* bb3  = (const float*)d_in[12];
  const float* fcw  = (const float*)d_in[13];
  const float* fcb  = (const float*)d_in[14];
  const float* sw1  = (const float*)d_in[15];
  const float* sb1  = (const float*)d_in[16];
  const float* sw2  = (const float*)d_in[17];
  const float* sb2  = (const float*)d_in[18];
  const float* sw3  = (const float*)d_in[19];
  const float* sb3  = (const float*)d_in[20];
  const float* sw4  = (const float*)d_in[21];
  const float* sb4  = (const float*)d_in[22];
  const float* cw1  = (const float*)d_in[23];
  const float* cb1  = (const float*)d_in[24];
  const float* cw2  = (const float*)d_in[25];
  const float* cb2  = (const float*)d_in[26];
  const float* cw3  = (const float*)d_in[27];
  const float* cb3  = (const float*)d_in[28];
  const float* cw4  = (const float*)d_in[29];
  const float* cb4  = (const float*)d_in[30];

  float* ws = (float*)d_ws;
  float* Ga      = ws;                   // 129600
  float* Gb      = ws + 129600;          // -> 259200
  float* bgagb   = ws + 259200;          // -> 259264
  float* act1pre = ws + 259264;          // 30720 -> 289984
  unsigned short* wsu = (unsigned short*)(ws + 289984);
  unsigned short* bfragGG   = wsu;              // 139264 sh
  unsigned short* act3      = wsu + 139264;     // 8812800 sh -> 8952064
  unsigned short* subjectsA = wsu + 8952064;    // 289792 sh -> 9241856
  unsigned short* w1T       = wsu + 9241856;    // 9306112 sh

  big_kernel<<<3525, 256, 0, stream>>>(x, w1c, b1c, g1, bb1, w2c, b2c, g2, bb2,
                                       w3c, b3c, g3, bb3, fcw, fcb, sw1, sb1,
                                       cw1, cb1, act3, bfragGG, bgagb,
                                       subjectsA, w1T, act1pre);
  gagb_kernel<<<254, 256, 0, stream>>>(act3, bfragGG, bgagb, Ga, Gb);
  sim_kernel<<<960, 256, 0, stream>>>(Ga, Gb, sw2, sb2, sw3, sb3, sw4, sb4, subjectsA);
  c1_kernel<<<256, 256, 0, stream>>>(subjectsA, w1T, act1pre);
  tail_kernel<<<30, 1024, 0, stream>>>(act1pre, cw2, cb2, cw3, cb3, cw4, cb4, (float*)d_out);
}